// Round 4
// baseline (61.665 us; speedup 1.0000x reference)
//
#include <hip/hip_runtime.h>
#include <math.h>

#define NB 4
#define FRAMES 400
#define NBINS 129
#define HOP 240
#define T_LEN (FRAMES * HOP)   // 96000
#define KLEN 256               // FIR length = 2*(NBINS-1)

// ---------------------------------------------------------------------------
// Kernel 1: per (b,frame) windowed minimum-phase FIR (256 taps), 128 threads.
// Thread n computes ker[n] AND ker[n+128] via parity split.
// Loop1 coefficients come from GLOBAL via scalar loads (uniform pointer);
// trig/exp via HW v_sin/v_cos/v_exp (v_sin takes REVOLUTIONS: angle n/256 is
// an exact argument). Loops 2/3 use float4 LDS broadcasts of block-computed
// data. Chebyshev recurrences supply cos/sin(k*n*2pi/256).
// ---------------------------------------------------------------------------
__global__ __launch_bounds__(128) void gen_fir(const float* __restrict__ log_mag,
                                               float* __restrict__ kern) {
    const int bf = blockIdx.x;   // 0..NB*FRAMES-1
    const int n  = threadIdx.x;  // 0..127

    __shared__ __align__(16) float  g[128];      // Xf[k]/128
    __shared__ __align__(16) float2 crci[128];   // (cr2[k], ci2[k]); k=0 pre-halved

    const float* lm = log_mag + bf * NBINS;      // block-uniform pointer -> s_load

    const float lmn = lm[n];                     // per-lane (vector load)
    // cos/sin(2*pi*n/256): HW trig in revolutions, argument n/256 exact
    const float rev_n = (float)n * (1.0f / 256.0f);
    const float ca = __builtin_amdgcn_cosf(rev_n);
    const float sa = __builtin_amdgcn_sinf(rev_n);
    const float a2  = 2.0f * ca;
    const float sgn = (n & 1) ? -1.0f : 1.0f;    // (-1)^n

    const float full0   = lm[0];                 // scalar loads (uniform)
    const float full128 = lm[128];

    // ---- Xf[n] = 2*sum_{m=0..127} lm[m] cos(mna) - lm[0] + sgn*lm[128]
    {
        float cm1 = ca, cm = 1.0f, acc = 0.0f;   // c_{-1}=cos(-a), c_0=1
#pragma unroll 8
        for (int m = 0; m < 128; ++m) {
            acc = fmaf(lm[m], cm, acc);          // lm[m] uniform -> SGPR operand
            const float cn = fmaf(a2, cm, -cm1); cm1 = cm; cm = cn;
        }
        const float Xf = 2.0f * acc - full0 + sgn * full128;
        g[n] = Xf * (1.0f / 128.0f);
    }
    __syncthreads();

    // ---- mp[n] = -sum_{k=0..127} g[k] sin(kna)   (k=0 term is 0)
    {
        const float4* g4p = (const float4*)g;
        float sm1 = -sa, sm = 0.0f, acc = 0.0f;  // s_{-1}=sin(-a), s_0=0
#pragma unroll 8
        for (int u = 0; u < 32; ++u) {
            const float4 gv = g4p[u];
            acc = fmaf(gv.x, sm, acc); { const float sn = fmaf(a2, sm, -sm1); sm1 = sm; sm = sn; }
            acc = fmaf(gv.y, sm, acc); { const float sn = fmaf(a2, sm, -sm1); sm1 = sm; sm = sn; }
            acc = fmaf(gv.z, sm, acc); { const float sn = fmaf(a2, sm, -sm1); sm1 = sm; sm = sn; }
            acc = fmaf(gv.w, sm, acc); { const float sn = fmaf(a2, sm, -sm1); sm1 = sm; sm = sn; }
        }
        const float mp = -acc;
        // e^lmn = 2^(lmn*log2 e); sin/cos(mp): to revolutions + fract-reduce
        const float e = __builtin_amdgcn_exp2f(lmn * 1.4426950408889634f);
        float rev = mp * 0.15915494309189535f;   // mp / (2*pi)
        rev = rev - floorf(rev);                 // v_fract reduction
        const float smp  = __builtin_amdgcn_sinf(rev);
        const float cmp_ = __builtin_amdgcn_cosf(rev);
        const float sc = (n == 0) ? 1.0f : 2.0f;
        crci[n] = make_float2(sc * e * cmp_, sc * e * smp);
    }
    __syncthreads();

    // ---- ker[n]     = (accE + accO + sgn*e128)/256
    //      ker[n+128] = (accE - accO + sgn*e128)/256 * (0.5+0.5*ca)
    {
        const float e128 = __builtin_amdgcn_exp2f(full128 * 1.4426950408889634f);
        const float4* cc4 = (const float4*)crci;
        float cm1 = ca, cm = 1.0f;     // k=0
        float sm1 = -sa, sm = 0.0f;
        float accE = 0.0f, accO = 0.0f;
#pragma unroll 8
        for (int u = 0; u < 64; ++u) {
            const float4 q = cc4[u];   // cr2[2u], ci2[2u], cr2[2u+1], ci2[2u+1]
            accE = fmaf(q.x, cm, accE); accE = fmaf(-q.y, sm, accE);
            { const float cn = fmaf(a2, cm, -cm1); cm1 = cm; cm = cn;
              const float sn = fmaf(a2, sm, -sm1); sm1 = sm; sm = sn; }
            accO = fmaf(q.z, cm, accO); accO = fmaf(-q.w, sm, accO);
            { const float cn = fmaf(a2, cm, -cm1); cm1 = cm; cm = cn;
              const float sn = fmaf(a2, sm, -sm1); sm1 = sm; sm = sn; }
        }
        const float base = sgn * e128;
        const float k0 = (accE + accO + base) * (1.0f / 256.0f);                      // wn = 1
        const float k1 = (accE - accO + base) * (1.0f / 256.0f) * (0.5f + 0.5f * ca); // hann tail
        kern[bf * KLEN + n]       = k0;
        kern[bf * KLEN + n + 128] = k1;
    }
}

// ---------------------------------------------------------------------------
// Kernel 2: time-varying FIR, LDS-free. 4 adjacent outputs per thread
// (4-aligned groups never straddle a frame boundary: boundaries at t=120 mod
// 240 are multiples of 4). x streamed from global with aligned float4 loads +
// a 4-register carry window; kernel taps read from global (quasi-uniform per
// wave -> single-line coalesced, L1-hot). 32 FMA per 3 VMEM loads.
// ---------------------------------------------------------------------------
__global__ __launch_bounds__(256) void fir_apply(const float* __restrict__ ex,
                                                 const float* __restrict__ kern,
                                                 float* __restrict__ out) {
    const int b   = blockIdx.y;
    const int tid = threadIdx.x;
    const int te  = blockIdx.x * 1024 + 4 * tid;   // outputs te..te+3
    if (te >= T_LEN) return;

    // interpolation params (lo shared by te..te+3)
    float s0 = ((float)te + 0.5f) * (1.0f / HOP) - 0.5f;
    s0 = fminf(fmaxf(s0, 0.0f), (float)(FRAMES - 1));
    const int lo = (int)s0;
    const int hi = min(lo + 1, FRAMES - 1);
    float w[4];
#pragma unroll
    for (int r = 0; r < 4; ++r) {
        float sr = ((float)(te + r) + 0.5f) * (1.0f / HOP) - 0.5f;
        sr = fminf(fmaxf(sr, 0.0f), (float)(FRAMES - 1));
        w[r] = sr - (float)lo;
    }

    const float* kL = kern + (b * FRAMES + lo) * KLEN;
    const float* kH = kern + (b * FRAMES + hi) * KLEN;
    const float* xp = ex + b * T_LEN + te;         // x[te+d] = xp[d]

    float aL0 = 0, aL1 = 0, aL2 = 0, aL3 = 0;
    float aH0 = 0, aH1 = 0, aH2 = 0, aH3 = 0;

    if (te >= 256) {
        // fast path: all x indices in-bounds, all loads 16B-aligned
        float4 Rp = *(const float4*)xp;            // x[te..te+3]
#pragma unroll 4
        for (int u = 0; u < 64; ++u) {
            const float4 Rc  = *(const float4*)(xp - 4 * u - 4); // x[te-4u-4..te-4u-1]
            const float4 kl4 = *(const float4*)(kL + 4 * u);
            const float4 kh4 = *(const float4*)(kH + 4 * u);
            // tap j=4u   : outputs use (Rp.x, Rp.y, Rp.z, Rp.w)
            aL0 = fmaf(Rp.x, kl4.x, aL0); aH0 = fmaf(Rp.x, kh4.x, aH0);
            aL1 = fmaf(Rp.y, kl4.x, aL1); aH1 = fmaf(Rp.y, kh4.x, aH1);
            aL2 = fmaf(Rp.z, kl4.x, aL2); aH2 = fmaf(Rp.z, kh4.x, aH2);
            aL3 = fmaf(Rp.w, kl4.x, aL3); aH3 = fmaf(Rp.w, kh4.x, aH3);
            // tap j=4u+1 : (Rc.w, Rp.x, Rp.y, Rp.z)
            aL0 = fmaf(Rc.w, kl4.y, aL0); aH0 = fmaf(Rc.w, kh4.y, aH0);
            aL1 = fmaf(Rp.x, kl4.y, aL1); aH1 = fmaf(Rp.x, kh4.y, aH1);
            aL2 = fmaf(Rp.y, kl4.y, aL2); aH2 = fmaf(Rp.y, kh4.y, aH2);
            aL3 = fmaf(Rp.z, kl4.y, aL3); aH3 = fmaf(Rp.z, kh4.y, aH3);
            // tap j=4u+2 : (Rc.z, Rc.w, Rp.x, Rp.y)
            aL0 = fmaf(Rc.z, kl4.z, aL0); aH0 = fmaf(Rc.z, kh4.z, aH0);
            aL1 = fmaf(Rc.w, kl4.z, aL1); aH1 = fmaf(Rc.w, kh4.z, aH1);
            aL2 = fmaf(Rp.x, kl4.z, aL2); aH2 = fmaf(Rp.x, kh4.z, aH2);
            aL3 = fmaf(Rp.y, kl4.z, aL3); aH3 = fmaf(Rp.y, kh4.z, aH3);
            // tap j=4u+3 : (Rc.y, Rc.z, Rc.w, Rp.x)
            aL0 = fmaf(Rc.y, kl4.w, aL0); aH0 = fmaf(Rc.y, kh4.w, aH0);
            aL1 = fmaf(Rc.z, kl4.w, aL1); aH1 = fmaf(Rc.z, kh4.w, aH1);
            aL2 = fmaf(Rc.w, kl4.w, aL2); aH2 = fmaf(Rc.w, kh4.w, aH2);
            aL3 = fmaf(Rp.x, kl4.w, aL3); aH3 = fmaf(Rp.x, kh4.w, aH3);
            Rp = Rc;
        }
    } else {
        // guarded path: only wave 0 of block 0 (te < 256)
        const float* xb = ex + b * T_LEN;
        for (int j = 0; j < KLEN; ++j) {
            const float klv = kL[j], khv = kH[j];
            float aLs[1];
            (void)aLs;
#pragma unroll
            for (int r = 0; r < 4; ++r) {
                const int idx = te + r - j;
                const float xv = (idx >= 0) ? xb[idx] : 0.0f;
                switch (r) {
                    case 0: aL0 = fmaf(xv, klv, aL0); aH0 = fmaf(xv, khv, aH0); break;
                    case 1: aL1 = fmaf(xv, klv, aL1); aH1 = fmaf(xv, khv, aH1); break;
                    case 2: aL2 = fmaf(xv, klv, aL2); aH2 = fmaf(xv, khv, aH2); break;
                    case 3: aL3 = fmaf(xv, klv, aL3); aH3 = fmaf(xv, khv, aH3); break;
                }
            }
        }
    }

    const float y0 = aL0 + w[0] * (aH0 - aL0);
    const float y1 = aL1 + w[1] * (aH1 - aL1);
    const float y2 = aL2 + w[2] * (aH2 - aL2);
    const float y3 = aL3 + w[3] * (aH3 - aL3);
    *(float4*)(out + b * T_LEN + te) = make_float4(y0, y1, y2, y3);
}

// ---------------------------------------------------------------------------
extern "C" void kernel_launch(void* const* d_in, const int* in_sizes, int n_in,
                              void* d_out, int out_size, void* d_ws, size_t ws_size,
                              hipStream_t stream) {
    const float* ex      = (const float*)d_in[0];
    const float* log_mag = (const float*)d_in[1];
    float* kern = (float*)d_ws;          // NB*FRAMES*KLEN floats = 1.6 MB
    float* out  = (float*)d_out;

    gen_fir<<<NB * FRAMES, 128, 0, stream>>>(log_mag, kern);

    dim3 grid((T_LEN + 1023) / 1024, NB);
    fir_apply<<<grid, 256, 0, stream>>>(ex, kern, out);
}

// Round 5
// 28.528 us; speedup vs baseline: 2.1616x; 2.1616x over previous
//
#include <hip/hip_runtime.h>
#include <math.h>

#define NB 4
#define FRAMES 400
#define NBINS 129
#define HOP 240
#define T_LEN (FRAMES * HOP)   // 96000
#define KLEN 256               // FIR length = 2*(NBINS-1)

#define REC_C { const float cn = fmaf(a2, cm, -cm1); cm1 = cm; cm = cn; }
#define REC_S { const float sn = fmaf(a2, sm, -sm1); sm1 = sm; sm = sn; }

// ---------------------------------------------------------------------------
// Kernel 1: per (b,frame) windowed minimum-phase FIR, ONE WAVE per frame.
// Thread n in [0,64) computes ker at N = n, n+64, n+128, n+192 via the mod-4
// phase fold: cos(theta*k*(n+64q)) = cos(theta*k*n + q*k*pi/2) -- the shift
// only permutes (cos,sin) with signs depending on k mod 4. One Chebyshev
// recurrence per thread serves all four outputs.
//   W_r = sum_{k==r (4)} (2C[k] cos - 2S[k] sin),  r=0..3
//   X_r = sum_{k==r (4)} (2C[k] sin + 2S[k] cos),  r=1,3 only
//   ker[n]     ~ W0+W1+W2+W3      ker[n+64]  ~ W0-X1-W2+X3
//   ker[n+128] ~ W0-W1+W2-W3      ker[n+192] ~ W0+X1-W2-X3
// Loop1 coefficients are uniform global reads (s_load); loops 2/3 read
// block-computed data as float4 LDS broadcasts. HW trig (revolutions).
// ---------------------------------------------------------------------------
__global__ __launch_bounds__(64) void gen_fir(const float* __restrict__ log_mag,
                                              float* __restrict__ kern) {
    const int bf = blockIdx.x;   // 0..NB*FRAMES-1
    const int n  = threadIdx.x;  // 0..63

    __shared__ __align__(16) float  g[128];      // Xf[k]/128
    __shared__ __align__(16) float2 crci[128];   // (wC[k], wS[k]); w=1 at k=0 else 2

    const float* lm = log_mag + bf * NBINS;      // block-uniform -> s_load

    const float lmn0 = lm[n];                    // per-lane coalesced
    const float lmn1 = lm[n + 64];

    const float rev_n = (float)n * (1.0f / 256.0f);
    const float ca = __builtin_amdgcn_cosf(rev_n);   // cos(2*pi*n/256)
    const float sa = __builtin_amdgcn_sinf(rev_n);
    const float a2  = 2.0f * ca;
    const float sgn = (n & 1) ? -1.0f : 1.0f;        // (-1)^n ( == (-1)^(n+64q) )

    const float f0s  = lm[0];                    // uniform
    const float f128 = lm[128];

    // ---- Loop 1: Xf[n], Xf[n+64].  U = sum lm[m] cos(theta m n), m=0..127;
    //      V = sum lm[m] cos(theta m (n+64)) via mod-4 phase table.
    {
        float cm1 = ca, cm = 1.0f, sm1 = -sa, sm = 0.0f;
        float U = 0.0f, V = 0.0f;
#pragma unroll
        for (int u = 0; u < 32; ++u) {
            float f;
            f = lm[4 * u + 0]; U = fmaf(f, cm, U); V = fmaf(f, cm, V);  REC_C; REC_S;
            f = lm[4 * u + 1]; U = fmaf(f, cm, U); V = fmaf(-f, sm, V); REC_C; REC_S;
            f = lm[4 * u + 2]; U = fmaf(f, cm, U); V = fmaf(-f, cm, V); REC_C; REC_S;
            f = lm[4 * u + 3]; U = fmaf(f, cm, U); V = fmaf(f, sm, V);  REC_C; REC_S;
        }
        // Xf[N] = -lm[0] + (-1)^n lm[128] + 2*sum_{m=0..127}
        const float base = -f0s + sgn * f128;
        g[n]      = (base + 2.0f * U) * (1.0f / 128.0f);
        g[n + 64] = (base + 2.0f * V) * (1.0f / 128.0f);
    }
    __syncthreads();

    // ---- Loop 2: mp[n] = -sum g[k] sin(theta k n); mp[n+64] via mod-4 table.
    {
        const float4* g4p = (const float4*)g;
        float cm1 = ca, cm = 1.0f, sm1 = -sa, sm = 0.0f;
        float U = 0.0f, V = 0.0f;
#pragma unroll
        for (int u = 0; u < 32; ++u) {
            const float4 gv = g4p[u];
            U = fmaf(gv.x, sm, U); V = fmaf(gv.x, sm, V);  REC_C; REC_S;   // k=4u
            U = fmaf(gv.y, sm, U); V = fmaf(gv.y, cm, V);  REC_C; REC_S;   // k=4u+1
            U = fmaf(gv.z, sm, U); V = fmaf(-gv.z, sm, V); REC_C; REC_S;   // k=4u+2
            U = fmaf(gv.w, sm, U); V = fmaf(-gv.w, cm, V); REC_C; REC_S;   // k=4u+3
        }
        const float mp0 = -U, mp1 = -V;
        const float e0 = __builtin_amdgcn_exp2f(lmn0 * 1.4426950408889634f);
        const float e1 = __builtin_amdgcn_exp2f(lmn1 * 1.4426950408889634f);
        float r0 = mp0 * 0.15915494309189535f; r0 -= floorf(r0);
        float r1 = mp1 * 0.15915494309189535f; r1 -= floorf(r1);
        const float w0 = (n == 0) ? 1.0f : 2.0f;
        crci[n]      = make_float2(w0 * e0 * __builtin_amdgcn_cosf(r0),
                                   w0 * e0 * __builtin_amdgcn_sinf(r0));
        crci[n + 64] = make_float2(2.0f * e1 * __builtin_amdgcn_cosf(r1),
                                   2.0f * e1 * __builtin_amdgcn_sinf(r1));
    }
    __syncthreads();

    // ---- Loop 3: W0..W3, X1, X3 -> four outputs.
    {
        const float4* cc4 = (const float4*)crci;
        float cm1 = ca, cm = 1.0f, sm1 = -sa, sm = 0.0f;
        float W0 = 0.0f, W1 = 0.0f, W2 = 0.0f, W3 = 0.0f, X1 = 0.0f, X3 = 0.0f;
#pragma unroll
        for (int u = 0; u < 32; ++u) {
            const float4 q1 = cc4[2 * u];       // C'[4u], S'[4u], C'[4u+1], S'[4u+1]
            const float4 q2 = cc4[2 * u + 1];   // C'[4u+2], S'[4u+2], C'[4u+3], S'[4u+3]
            W0 = fmaf(q1.x, cm, W0); W0 = fmaf(-q1.y, sm, W0); REC_C; REC_S;   // k=4u
            W1 = fmaf(q1.z, cm, W1); W1 = fmaf(-q1.w, sm, W1);
            X1 = fmaf(q1.z, sm, X1); X1 = fmaf(q1.w, cm, X1);  REC_C; REC_S;   // k=4u+1
            W2 = fmaf(q2.x, cm, W2); W2 = fmaf(-q2.y, sm, W2); REC_C; REC_S;   // k=4u+2
            W3 = fmaf(q2.z, cm, W3); W3 = fmaf(-q2.w, sm, W3);
            X3 = fmaf(q2.z, sm, X3); X3 = fmaf(q2.w, cm, X3);  REC_C; REC_S;   // k=4u+3
        }
        const float e128 = __builtin_amdgcn_exp2f(f128 * 1.4426950408889634f);
        const float base = sgn * e128;
        const float s = 1.0f / 256.0f;
        float* kp = kern + bf * KLEN;
        kp[n]       = (W0 + W1 + W2 + W3 + base) * s;                          // hann=1
        kp[n + 64]  = (W0 - X1 - W2 + X3 + base) * s;                          // hann=1
        kp[n + 128] = (W0 - W1 + W2 - W3 + base) * s * (0.5f + 0.5f * ca);     // tail
        kp[n + 192] = (W0 + X1 - W2 - X3 + base) * s * (0.5f - 0.5f * sa);     // tail
    }
}

// ---------------------------------------------------------------------------
// Kernel 2: time-varying FIR, LDS-staged (round-3 structure), 4 outputs per
// thread. 4-aligned output groups share lo (boundaries at t=120 mod 240 are
// multiples of 4). x via aligned ds_read_b128 + 4-register carry; kernels
// staged as (kL,kH) float2 pairs -> one b128 = 2 taps of both kernels.
// Per thread: 65 + 128 = 193 b128 LDS reads for 2048 FMAs.
// ---------------------------------------------------------------------------
__global__ __launch_bounds__(128) void fir_apply(const float* __restrict__ ex,
                                                 const float* __restrict__ kern,
                                                 float* __restrict__ out) {
    const int b   = blockIdx.y;
    const int t0  = blockIdx.x * 512;
    const int tid = threadIdx.x;

    __shared__ __align__(16) float  xs[768];        // x[t0-256 .. t0+511]
    __shared__ __align__(16) float2 kp[4][258];     // (kerLo, kerHi) per q; pad 2

    // ---- stage x
    const float* xb = ex + b * T_LEN;
    if (t0 >= 256 && t0 + 512 <= T_LEN) {
        float4* xs4 = (float4*)xs;
        const float4* src = (const float4*)(xb + t0 - 256);
#pragma unroll
        for (int i = tid; i < 192; i += 128) xs4[i] = src[i];
    } else {
        for (int i = tid; i < 768; i += 128) {
            const int t = t0 - 256 + i;
            xs[i] = (t >= 0 && t < T_LEN) ? xb[t] : 0.0f;
        }
    }

    // ---- stage kernels f0..f0+3 (clamped), interleaved (kL,kH)
    float src0 = ((float)t0 + 0.5f) * (1.0f / HOP) - 0.5f;
    src0 = fminf(fmaxf(src0, 0.0f), (float)(FRAMES - 1));
    const int f0 = (int)src0;
    const float* kb = kern + b * FRAMES * KLEN;
    for (int i = tid; i < 512; i += 128) {
        const int q  = i >> 7;
        const int jj = (i & 127) * 2;
        const int fl = min(f0 + q,     FRAMES - 1);
        const int fh = min(f0 + q + 1, FRAMES - 1);
        const float2 lv = *(const float2*)&kb[fl * KLEN + jj];
        const float2 hv = *(const float2*)&kb[fh * KLEN + jj];
        kp[q][jj]     = make_float2(lv.x, hv.x);
        kp[q][jj + 1] = make_float2(lv.y, hv.y);
    }
    __syncthreads();

    const int te = t0 + 4 * tid;
    if (te >= T_LEN) return;     // only last block's upper half

    float s0 = ((float)te + 0.5f) * (1.0f / HOP) - 0.5f;
    s0 = fminf(fmaxf(s0, 0.0f), (float)(FRAMES - 1));
    const int lo = (int)s0;
    float w[4];
#pragma unroll
    for (int r = 0; r < 4; ++r) {
        float sr = ((float)(te + r) + 0.5f) * (1.0f / HOP) - 0.5f;
        sr = fminf(fmaxf(sr, 0.0f), (float)(FRAMES - 1));
        w[r] = sr - (float)lo;
    }

    const float4* kq4 = (const float4*)&kp[lo - f0][0];  // (kL[2v],kH[2v],kL[2v+1],kH[2v+1])
    const int base = 4 * tid;                            // xs index of x[te] is base+256

    float aL0 = 0, aL1 = 0, aL2 = 0, aL3 = 0;
    float aH0 = 0, aH1 = 0, aH2 = 0, aH3 = 0;
    float4 Rp = *(const float4*)&xs[base + 256];         // x[te..te+3]
#pragma unroll 4
    for (int u = 0; u < 64; ++u) {
        const float4 Rc  = *(const float4*)&xs[base + 252 - 4 * u];  // x[te-4u-4 .. te-4u-1]
        const float4 k4a = kq4[2 * u];        // taps 4u, 4u+1
        const float4 k4b = kq4[2 * u + 1];    // taps 4u+2, 4u+3
        // tap j=4u   : windows (Rp.x,Rp.y,Rp.z,Rp.w)
        aL0 = fmaf(Rp.x, k4a.x, aL0); aH0 = fmaf(Rp.x, k4a.y, aH0);
        aL1 = fmaf(Rp.y, k4a.x, aL1); aH1 = fmaf(Rp.y, k4a.y, aH1);
        aL2 = fmaf(Rp.z, k4a.x, aL2); aH2 = fmaf(Rp.z, k4a.y, aH2);
        aL3 = fmaf(Rp.w, k4a.x, aL3); aH3 = fmaf(Rp.w, k4a.y, aH3);
        // tap j=4u+1 : (Rc.w,Rp.x,Rp.y,Rp.z)
        aL0 = fmaf(Rc.w, k4a.z, aL0); aH0 = fmaf(Rc.w, k4a.w, aH0);
        aL1 = fmaf(Rp.x, k4a.z, aL1); aH1 = fmaf(Rp.x, k4a.w, aH1);
        aL2 = fmaf(Rp.y, k4a.z, aL2); aH2 = fmaf(Rp.y, k4a.w, aH2);
        aL3 = fmaf(Rp.z, k4a.z, aL3); aH3 = fmaf(Rp.z, k4a.w, aH3);
        // tap j=4u+2 : (Rc.z,Rc.w,Rp.x,Rp.y)
        aL0 = fmaf(Rc.z, k4b.x, aL0); aH0 = fmaf(Rc.z, k4b.y, aH0);
        aL1 = fmaf(Rc.w, k4b.x, aL1); aH1 = fmaf(Rc.w, k4b.y, aH1);
        aL2 = fmaf(Rp.x, k4b.x, aL2); aH2 = fmaf(Rp.x, k4b.y, aH2);
        aL3 = fmaf(Rp.y, k4b.x, aL3); aH3 = fmaf(Rp.y, k4b.y, aH3);
        // tap j=4u+3 : (Rc.y,Rc.z,Rc.w,Rp.x)
        aL0 = fmaf(Rc.y, k4b.z, aL0); aH0 = fmaf(Rc.y, k4b.w, aH0);
        aL1 = fmaf(Rc.z, k4b.z, aL1); aH1 = fmaf(Rc.z, k4b.w, aH1);
        aL2 = fmaf(Rc.w, k4b.z, aL2); aH2 = fmaf(Rc.w, k4b.w, aH2);
        aL3 = fmaf(Rp.x, k4b.z, aL3); aH3 = fmaf(Rp.x, k4b.w, aH3);
        Rp = Rc;
    }

    const float y0 = aL0 + w[0] * (aH0 - aL0);
    const float y1 = aL1 + w[1] * (aH1 - aL1);
    const float y2 = aL2 + w[2] * (aH2 - aL2);
    const float y3 = aL3 + w[3] * (aH3 - aL3);
    *(float4*)(out + b * T_LEN + te) = make_float4(y0, y1, y2, y3);
}

// ---------------------------------------------------------------------------
extern "C" void kernel_launch(void* const* d_in, const int* in_sizes, int n_in,
                              void* d_out, int out_size, void* d_ws, size_t ws_size,
                              hipStream_t stream) {
    const float* ex      = (const float*)d_in[0];
    const float* log_mag = (const float*)d_in[1];
    float* kern = (float*)d_ws;          // NB*FRAMES*KLEN floats = 1.6 MB
    float* out  = (float*)d_out;

    gen_fir<<<NB * FRAMES, 64, 0, stream>>>(log_mag, kern);

    dim3 grid((T_LEN + 511) / 512, NB);
    fir_apply<<<grid, 128, 0, stream>>>(ex, kern, out);
}

// Round 6
// 25.947 us; speedup vs baseline: 2.3766x; 1.0995x over previous
//
#include <hip/hip_runtime.h>
#include <math.h>

#define NB 4
#define FRAMES 400
#define NBINS 129
#define HOP 240
#define T_LEN (FRAMES * HOP)   // 96000
#define KLEN 256               // FIR length = 2*(NBINS-1)

#define REC_C { const float cn = fmaf(a2, cm, -cm1); cm1 = cm; cm = cn; }
#define REC_S { const float sn = fmaf(a2, sm, -sm1); sm1 = sm; sm = sn; }

// ---------------------------------------------------------------------------
// Kernel 1: per (b,frame) windowed minimum-phase FIR (256 taps), 128 threads.
// Round-3-proven structure (parity split: thread n -> ker[n], ker[n+128];
// float4 LDS broadcasts; Chebyshev recurrences) with HW trig/exp replacing
// libm (v_sin/v_cos take REVOLUTIONS; n/256 rev is an exact argument).
// ---------------------------------------------------------------------------
__global__ __launch_bounds__(128) void gen_fir(const float* __restrict__ log_mag,
                                               float* __restrict__ kern) {
    const int bf = blockIdx.x;   // 0..NB*FRAMES-1
    const int n  = threadIdx.x;  // 0..127

    __shared__ __align__(16) float  full[132];   // lm[0..128]
    __shared__ __align__(16) float  g[128];      // Xf[k]/128
    __shared__ __align__(16) float2 crci[128];   // (wC[k], wS[k]); w=1 at k=0 else 2

    const float* lm = log_mag + bf * NBINS;
    full[n] = lm[n];
    if (n == 0) full[128] = lm[128];

    const float rev_n = (float)n * (1.0f / 256.0f);
    const float ca = __builtin_amdgcn_cosf(rev_n);   // cos(2*pi*n/256)
    const float sa = __builtin_amdgcn_sinf(rev_n);
    const float a2  = 2.0f * ca;
    const float sgn = (n & 1) ? -1.0f : 1.0f;        // (-1)^n
    __syncthreads();

    const float full0   = full[0];
    const float full128 = full[128];

    // ---- Xf[n] = 2*sum_{m=0..127} full[m] cos(mna) - full[0] + sgn*full[128]
    {
        const float4* f4p = (const float4*)full;
        float cm1 = ca, cm = 1.0f, acc = 0.0f;       // c_{-1}=cos(-a), c_0=1
#pragma unroll 8
        for (int u = 0; u < 32; ++u) {
            const float4 f4 = f4p[u];
            acc = fmaf(f4.x, cm, acc); REC_C;
            acc = fmaf(f4.y, cm, acc); REC_C;
            acc = fmaf(f4.z, cm, acc); REC_C;
            acc = fmaf(f4.w, cm, acc); REC_C;
        }
        const float Xf = 2.0f * acc - full0 + sgn * full128;
        g[n] = Xf * (1.0f / 128.0f);
    }
    __syncthreads();

    // ---- mp[n] = -sum_{k=0..127} g[k] sin(kna)   (k=0 term is 0)
    {
        const float4* g4p = (const float4*)g;
        float sm1 = -sa, sm = 0.0f, acc = 0.0f;      // s_{-1}=sin(-a), s_0=0
#pragma unroll 8
        for (int u = 0; u < 32; ++u) {
            const float4 gv = g4p[u];
            acc = fmaf(gv.x, sm, acc); REC_S;
            acc = fmaf(gv.y, sm, acc); REC_S;
            acc = fmaf(gv.z, sm, acc); REC_S;
            acc = fmaf(gv.w, sm, acc); REC_S;
        }
        const float mp = -acc;
        const float e  = __builtin_amdgcn_exp2f(full[n] * 1.4426950408889634f);
        float rev = mp * 0.15915494309189535f;       // mp / (2*pi)
        rev = rev - floorf(rev);                     // v_fract reduction
        const float smp  = __builtin_amdgcn_sinf(rev);
        const float cmp_ = __builtin_amdgcn_cosf(rev);
        const float sc = (n == 0) ? 1.0f : 2.0f;
        crci[n] = make_float2(sc * e * cmp_, sc * e * smp);
    }
    __syncthreads();

    // ---- ker[n]     = (accE + accO + sgn*e128)/256          (hann = 1)
    //      ker[n+128] = (accE - accO + sgn*e128)/256*(0.5+0.5ca)
    {
        const float e128 = __builtin_amdgcn_exp2f(full128 * 1.4426950408889634f);
        const float4* cc4 = (const float4*)crci;
        float cm1 = ca, cm = 1.0f;     // k=0
        float sm1 = -sa, sm = 0.0f;
        float accE = 0.0f, accO = 0.0f;
#pragma unroll 8
        for (int u = 0; u < 64; ++u) {
            const float4 q = cc4[u];   // C'[2u], S'[2u], C'[2u+1], S'[2u+1]
            accE = fmaf(q.x, cm, accE); accE = fmaf(-q.y, sm, accE);
            REC_C; REC_S;
            accO = fmaf(q.z, cm, accO); accO = fmaf(-q.w, sm, accO);
            REC_C; REC_S;
        }
        const float base = sgn * e128;
        const float s = 1.0f / 256.0f;
        kern[bf * KLEN + n]       = (accE + accO + base) * s;
        kern[bf * KLEN + n + 128] = (accE - accO + base) * s * (0.5f + 0.5f * ca);
    }
}

// ---------------------------------------------------------------------------
// Kernel 2: time-varying FIR, frame-segment-aligned blocks. Segment bs covers
// outputs [start,end) that all share (lo,hi) = (f, min(f+1,399)):
//   bs=0: [0,120) f=0; bs=1..399: [240bs-120, 240bs+120) f=bs-1;
//   bs=400: [95880,96000) f=399.
// Kernel rows are therefore BLOCK-UNIFORM -> read from global with uniform
// float4 addresses (SMEM/L1 broadcast, zero LDS traffic). LDS holds only the
// x window; per-thread 2 adjacent outputs via the round-3 b64+carry pattern.
// Per thread: 128 b64 LDS reads, 128 uniform float4 k loads, 1024 FMA.
// ---------------------------------------------------------------------------
__global__ __launch_bounds__(128) void fir_apply(const float* __restrict__ ex,
                                                 const float* __restrict__ kern,
                                                 float* __restrict__ out) {
    const int b   = blockIdx.y;
    const int bs  = blockIdx.x;               // 0..400
    const int tid = threadIdx.x;

    const int start = (bs == 0) ? 0 : 240 * bs - 120;
    const int end   = min(T_LEN, 240 * bs + 120);
    const int f     = (bs == 0) ? 0 : bs - 1;
    const int fh    = min(f + 1, FRAMES - 1);

    __shared__ float xs[496];                 // x[start-255 .. start+240]

    const float* xb = ex + b * T_LEN;
    for (int i = tid; i < 496; i += 128) {
        const int t = start - 255 + i;
        xs[i] = (t >= 0 && t < T_LEN) ? xb[t] : 0.0f;
    }
    __syncthreads();

    const int te = start + 2 * tid;
    if (te >= end) return;

    // interpolation weights (lo = f for the whole block by construction)
    float se = ((float)te + 0.5f) * (1.0f / HOP) - 0.5f;
    se = fminf(fmaxf(se, 0.0f), (float)(FRAMES - 1));
    float so = ((float)te + 1.5f) * (1.0f / HOP) - 0.5f;
    so = fminf(fmaxf(so, 0.0f), (float)(FRAMES - 1));
    const float we = se - (float)f;
    const float wo = so - (float)f;

    const float* kL = kern + (b * FRAMES + f)  * KLEN;   // block-uniform rows
    const float* kH = kern + (b * FRAMES + fh) * KLEN;

    // x[te-j] = xs[255 + 2*tid - j]
    const int base = 2 * tid;
    float carry = xs[base + 256];             // x[te+1]
    float aeL = 0.0f, aeH = 0.0f, aoL = 0.0f, aoH = 0.0f;
#pragma unroll 4
    for (int u = 0; u < 64; ++u) {
        const float2 v1 = *(const float2*)&xs[base + 254 - 4 * u];  // x[te-4u-1], x[te-4u]
        const float2 v0 = *(const float2*)&xs[base + 252 - 4 * u];  // x[te-4u-3], x[te-4u-2]
        const float4 kl4 = *(const float4*)(kL + 4 * u);            // uniform
        const float4 kh4 = *(const float4*)(kH + 4 * u);            // uniform
        // tap j=4u   : e->v1.y  o->carry
        aeL = fmaf(v1.y,  kl4.x, aeL); aeH = fmaf(v1.y,  kh4.x, aeH);
        aoL = fmaf(carry, kl4.x, aoL); aoH = fmaf(carry, kh4.x, aoH);
        // tap j=4u+1 : e->v1.x  o->v1.y
        aeL = fmaf(v1.x,  kl4.y, aeL); aeH = fmaf(v1.x,  kh4.y, aeH);
        aoL = fmaf(v1.y,  kl4.y, aoL); aoH = fmaf(v1.y,  kh4.y, aoH);
        // tap j=4u+2 : e->v0.y  o->v1.x
        aeL = fmaf(v0.y,  kl4.z, aeL); aeH = fmaf(v0.y,  kh4.z, aeH);
        aoL = fmaf(v1.x,  kl4.z, aoL); aoH = fmaf(v1.x,  kh4.z, aoH);
        // tap j=4u+3 : e->v0.x  o->v0.y
        aeL = fmaf(v0.x,  kl4.w, aeL); aeH = fmaf(v0.x,  kh4.w, aeH);
        aoL = fmaf(v0.y,  kl4.w, aoL); aoH = fmaf(v0.y,  kh4.w, aoH);
        carry = v0.x;
    }

    const float y0 = aeL + we * (aeH - aeL);
    const float y1 = aoL + wo * (aoH - aoL);
    *(float2*)(out + b * T_LEN + te) = make_float2(y0, y1);  // te even -> aligned
}

// ---------------------------------------------------------------------------
extern "C" void kernel_launch(void* const* d_in, const int* in_sizes, int n_in,
                              void* d_out, int out_size, void* d_ws, size_t ws_size,
                              hipStream_t stream) {
    const float* ex      = (const float*)d_in[0];
    const float* log_mag = (const float*)d_in[1];
    float* kern = (float*)d_ws;          // NB*FRAMES*KLEN floats = 1.6 MB
    float* out  = (float*)d_out;

    gen_fir<<<NB * FRAMES, 128, 0, stream>>>(log_mag, kern);

    dim3 grid(401, NB);                  // 401 frame-aligned segments per batch
    fir_apply<<<grid, 128, 0, stream>>>(ex, kern, out);
}